// Round 3
// baseline (243.165 us; speedup 1.0000x reference)
//
#include <hip/hip_runtime.h>

// Problem constants (from reference setup_inputs)
#define L_DIM 12
#define B_DIM 8
#define H_DIM 12
#define S_DIM 384
#define S2    (S_DIM * S_DIM)   // 147456
#define M_DIM 32
#define NL 3
#define NH 4

// ---- dedup design ----
#define CHB   64                  // st elements per block
#define NCHB  (S2 / CHB)          // 2304 blocks
#define RED1  24                  // chunks summed per red1 block
#define NRED1 (NCHB / RED1)       // 96
#define MAXP  152                 // padded plane slots (<=144 used +4 prefetch pad)
#define MAXE  384                 // max sparse entries (32 m * 12 planes)
#define PART_ELEMS (NCHB * M_DIM * B_DIM)   // 589824 floats
// meta int layout inside ws (after part):
//  mi[0]=np4  mi[1]=ne
//  mi[8 .. 8+MAXP)        plane base offsets (element offset of (l,h) plane)
//  mi[160 .. 160+MAXP)    plane entry-offset prefix (np4+1 valid)
//  mi[320 .. 320+MAXE)    entry m
//  mi[704 .. 704+MAXE)    entry w (float bits)
#define META_INTS 1092

// ---------------- setup: build global sparse plane->(m,w) lists ----------------
__global__ __launch_bounds__(256) void pfe_setup(
    const int* __restrict__ lidx, const int* __restrict__ hidx, int* __restrict__ mi)
{
    __shared__ int cl[M_DIM][L_DIM], ch[M_DIM][H_DIM];
    __shared__ int cnt[144], map[144], offL[145];
    const int t = threadIdx.x;
    if (t < M_DIM) {
        for (int l = 0; l < L_DIM; ++l) cl[t][l] = 0;
        for (int h = 0; h < H_DIM; ++h) ch[t][h] = 0;
        for (int i = 0; i < NL; ++i) cl[t][lidx[t * NL + i]]++;
        for (int j = 0; j < NH; ++j) ch[t][hidx[t * NH + j]]++;
    }
    __syncthreads();
    if (t < 144) {
        const int l = t / H_DIM, h = t % H_DIM;
        int c = 0;
        for (int m = 0; m < M_DIM; ++m) c += (cl[m][l] && ch[m][h]) ? 1 : 0;
        cnt[t] = c;
    }
    __syncthreads();
    if (t == 0) {
        int np = 0, run = 0;
        for (int k = 0; k < 144; ++k) {
            if (cnt[k]) {
                map[k] = np;
                const int l = k / H_DIM, h = k % H_DIM;
                mi[8 + np] = (l * (B_DIM * H_DIM) + h) * S2;  // element offset, b=0
                offL[np] = run;
                run += cnt[k];
                ++np;
            } else map[k] = -1;
        }
        const int np4 = (np + 3) & ~3;
        for (int p = np; p < np4 + 4; ++p) mi[8 + p] = mi[8 + np - 1];  // prefetch pad
        for (int p = np; p <= np4; ++p) offL[p] = run;                  // empty pads
        for (int p = 0; p <= np4; ++p) mi[160 + p] = offL[p];
        mi[0] = np4;
        mi[1] = run;
    }
    __syncthreads();
    if (t < 144 && map[t] >= 0) {
        const int l = t / H_DIM, h = t % H_DIM;
        int pos = offL[map[t]];
        for (int m = 0; m < M_DIM; ++m) {
            const int w = cl[m][l] * ch[m][h];
            if (w) {
                mi[320 + pos] = m;
                reinterpret_cast<float*>(mi)[704 + pos] = (float)w * (1.0f / 12.0f);
                ++pos;
            }
        }
    }
}

// ---------------- main: one block per 64-elem st chunk, full dedup ----------------
__global__ __launch_bounds__(256) void pfe_dedup(
    const float* __restrict__ attn,
    const float* __restrict__ refs,
    const int*   __restrict__ mi,
    float*       __restrict__ part)   // [NCHB][256]
{
    __shared__ float pm[M_DIM * B_DIM * CHB];   // 64 KB: pm[m][b][stl]
    __shared__ int   s_base[MAXP];
    __shared__ int   s_off[MAXP];
    __shared__ int   s_em[MAXE];
    __shared__ float s_ew[MAXE];

    const int t = threadIdx.x;
    const int chunk = blockIdx.x;
    const int np4 = mi[0];
    const int ne  = mi[1];

    for (int i = t; i < np4 + 4; i += 256) s_base[i] = mi[8 + i];
    for (int i = t; i <= np4;    i += 256) s_off[i]  = mi[160 + i];
    for (int i = t; i < ne;      i += 256) { s_em[i] = mi[320 + i];
                                             s_ew[i] = reinterpret_cast<const float*>(mi)[704 + i]; }
    float2* pmv = reinterpret_cast<float2*>(pm);
    for (int i = t; i < M_DIM * B_DIM * CHB / 2; i += 256) pmv[i] = make_float2(0.f, 0.f);
    __syncthreads();

    // thread owns (b, stl-pair): b = t>>5, stl = (t&31)*2
    const int b  = t >> 5;
    const int sq = t & 31;
    const unsigned toff = (unsigned)(b * H_DIM) * (unsigned)S2
                        + (unsigned)chunk * (unsigned)CHB + (unsigned)sq * 2u;
    const float* ap = attn + toff;
    float2* myp = pmv + b * (CHB / 2) + sq;

#define LD(q) (*reinterpret_cast<const float2*>(ap + s_base[q]))
#define PROC(P, V)                                                        \
    {                                                                     \
        const int e1 = s_off[(P) + 1];                                    \
        for (int e = s_off[P]; e < e1; ++e) {                             \
            float2* pp = myp + s_em[e] * (B_DIM * CHB / 2);               \
            const float w = s_ew[e];                                      \
            float2 c = *pp;                                               \
            c.x = fmaf(w, (V).x, c.x);                                    \
            c.y = fmaf(w, (V).y, c.y);                                    \
            *pp = c;                                                      \
        }                                                                 \
    }

    float2 v0 = LD(0), v1 = LD(1), v2 = LD(2), v3 = LD(3);
    for (int p = 0; p < np4; p += 4) {
        PROC(p + 0, v0); v0 = LD(p + 4);
        PROC(p + 1, v1); v1 = LD(p + 5);
        PROC(p + 2, v2); v2 = LD(p + 6);
        PROC(p + 3, v3); v3 = LD(p + 7);
    }
#undef PROC
#undef LD
    __syncthreads();

    // ---- phase A: per (m,stl) stats; overwrite pm with z values ----
    for (int q = 0; q < 8; ++q) {
        const int tau = t + 256 * q;
        const int mm = tau >> 6;       // wave-uniform
        const int sl = tau & 63;       // consecutive across lanes
        float x[B_DIM];
        float mu = 0.f;
#pragma unroll
        for (int bb = 0; bb < B_DIM; ++bb) {
            x[bb] = pm[(mm * B_DIM + bb) * CHB + sl];
            mu += x[bb];
        }
        mu *= 0.125f;
        float ssum = 0.f;
#pragma unroll
        for (int bb = 0; bb < B_DIM; ++bb) {
            const float d = x[bb] - mu;
            ssum = fmaf(d, d, ssum);
        }
        const float inv = 1.0f / fmaxf(sqrtf(ssum * (1.0f / 7.0f)), 1e-8f);
        const float rv = refs[(unsigned)mm * (unsigned)S2 + (unsigned)chunk * CHB + (unsigned)sl];
#pragma unroll
        for (int bb = 0; bb < B_DIM; ++bb)
            pm[(mm * B_DIM + bb) * CHB + sl] = (x[bb] - rv) * inv;
    }
    __syncthreads();

    // ---- phase B: thread (m,b) sums z^2 over stl (staggered, 2-way max) ----
    const int mB = t >> 3, bB = t & 7;
    float acc = 0.f;
#pragma unroll
    for (int s = 0; s < CHB; ++s) {
        const int sl = (s + t) & (CHB - 1);
        const float z = pm[(mB * B_DIM + bB) * CHB + sl];
        acc = fmaf(z, z, acc);
    }
    part[chunk * 256 + t] = acc;
}

// ---------------- deterministic two-stage reduction ----------------
__global__ __launch_bounds__(256) void pfe_red1(
    const float* __restrict__ part, float* __restrict__ mid)
{
    const int t = threadIdx.x;
    const int c0 = blockIdx.x * RED1;
    float s = 0.f;
#pragma unroll
    for (int i = 0; i < RED1; ++i) s += part[(c0 + i) * 256 + t];
    mid[blockIdx.x * 256 + t] = s;
}

__global__ __launch_bounds__(256) void pfe_red2(
    const float* __restrict__ mid, float* __restrict__ out)
{
    const int t = threadIdx.x;
    float s = 0.f;
#pragma unroll
    for (int i = 0; i < NRED1; ++i) s += mid[i * 256 + t];
    out[(t & 7) * M_DIM + (t >> 3)] = s * (1.0f / (float)S2);
}

// ---------------- fallback path (tiny ws): v2 atomic kernel ----------------
__global__ void pfe_zero(float* __restrict__ out) {
    if (threadIdx.x < M_DIM * B_DIM) out[threadIdx.x] = 0.f;
}

#define FCH 512
#define FNCH (S2 / FCH)
__global__ __launch_bounds__(128) void pfe_fallback(
    const float* __restrict__ attn, const float* __restrict__ refs,
    const int* __restrict__ lidx, const int* __restrict__ hidx,
    float* __restrict__ out)
{
    const int p = blockIdx.x;
    const int m = p & (M_DIM - 1);
    const int chunk = p >> 5;
    const int tid = threadIdx.x;
    const unsigned st = (unsigned)chunk * FCH + (unsigned)tid * 4;

    __shared__ int   s_mk[NL * NH];
    __shared__ float s_mw[NL * NH];
    __shared__ int   s_nm;
    __shared__ float s_red[2 * B_DIM];

    if (tid == 0) {
        int keys[NL * NH];
        for (int i = 0; i < NL; ++i) {
            const int l = lidx[m * NL + i];
            for (int j = 0; j < NH; ++j) keys[i * NH + j] = l * 16 + hidx[m * NH + j];
        }
        for (int i = 1; i < NL * NH; ++i) {
            const int k = keys[i]; int j = i - 1;
            for (; j >= 0 && keys[j] > k; --j) keys[j + 1] = keys[j];
            keys[j + 1] = k;
        }
        int nm = 0;
        for (int i = 0; i < NL * NH; ++i) {
            if (nm > 0 && s_mk[nm - 1] == keys[i]) s_mw[nm - 1] += 1.0f;
            else { s_mk[nm] = keys[i]; s_mw[nm] = 1.0f; ++nm; }
        }
        s_nm = nm;
    }
    __syncthreads();

    const float4 r = *reinterpret_cast<const float4*>(refs + (unsigned)m * (unsigned)S2 + st);
    float4 acc[B_DIM];
    for (int bb = 0; bb < B_DIM; ++bb) acc[bb] = make_float4(0.f, 0.f, 0.f, 0.f);
    const int nm = s_nm;
    for (int e = 0; e < nm; ++e) {
        const int k = s_mk[e]; const float w = s_mw[e];
        const int l = k >> 4, h = k & 15;
        const unsigned base = (unsigned)(l * (B_DIM * H_DIM) + h) * (unsigned)S2 + st;
        for (int bb = 0; bb < B_DIM; ++bb) {
            const float4 v = *reinterpret_cast<const float4*>(
                attn + base + (unsigned)bb * (unsigned)(H_DIM * S2));
            acc[bb].x = fmaf(w, v.x, acc[bb].x); acc[bb].y = fmaf(w, v.y, acc[bb].y);
            acc[bb].z = fmaf(w, v.z, acc[bb].z); acc[bb].w = fmaf(w, v.w, acc[bb].w);
        }
    }
    const float c12 = 1.0f / 12.0f;
    float4 pmv[B_DIM];
    for (int bb = 0; bb < B_DIM; ++bb) {
        pmv[bb].x = acc[bb].x * c12; pmv[bb].y = acc[bb].y * c12;
        pmv[bb].z = acc[bb].z * c12; pmv[bb].w = acc[bb].w * c12;
    }
    float4 mu = make_float4(0.f, 0.f, 0.f, 0.f);
    for (int bb = 0; bb < B_DIM; ++bb) {
        mu.x += pmv[bb].x; mu.y += pmv[bb].y; mu.z += pmv[bb].z; mu.w += pmv[bb].w;
    }
    mu.x *= 0.125f; mu.y *= 0.125f; mu.z *= 0.125f; mu.w *= 0.125f;
    float4 ss = make_float4(0.f, 0.f, 0.f, 0.f);
    for (int bb = 0; bb < B_DIM; ++bb) {
        const float dx = pmv[bb].x - mu.x, dy = pmv[bb].y - mu.y,
                    dz = pmv[bb].z - mu.z, dw = pmv[bb].w - mu.w;
        ss.x += dx * dx; ss.y += dy * dy; ss.z += dz * dz; ss.w += dw * dw;
    }
    const float c7 = 1.0f / 7.0f;
    float4 inv;
    inv.x = 1.0f / fmaxf(sqrtf(ss.x * c7), 1e-8f);
    inv.y = 1.0f / fmaxf(sqrtf(ss.y * c7), 1e-8f);
    inv.z = 1.0f / fmaxf(sqrtf(ss.z * c7), 1e-8f);
    inv.w = 1.0f / fmaxf(sqrtf(ss.w * c7), 1e-8f);
    float s[B_DIM];
    for (int bb = 0; bb < B_DIM; ++bb) {
        const float zx = (pmv[bb].x - r.x) * inv.x;
        const float zy = (pmv[bb].y - r.y) * inv.y;
        const float zz = (pmv[bb].z - r.z) * inv.z;
        const float zw = (pmv[bb].w - r.w) * inv.w;
        s[bb] = zx * zx + zy * zy + zz * zz + zw * zw;
    }
    for (int bb = 0; bb < B_DIM; ++bb) {
        float v = s[bb];
        for (int off = 32; off > 0; off >>= 1) v += __shfl_down(v, off);
        s[bb] = v;
    }
    const int lane = tid & 63, wave = tid >> 6;
    if (lane == 0) for (int bb = 0; bb < B_DIM; ++bb) s_red[wave * B_DIM + bb] = s[bb];
    __syncthreads();
    if (tid < B_DIM) {
        const float tot = (s_red[tid] + s_red[B_DIM + tid]) * (1.0f / (float)S2);
        atomicAdd(&out[tid * M_DIM + m], tot);
    }
}

extern "C" void kernel_launch(void* const* d_in, const int* in_sizes, int n_in,
                              void* d_out, int out_size, void* d_ws, size_t ws_size,
                              hipStream_t stream) {
    const float* attn = (const float*)d_in[0];
    const float* refs = (const float*)d_in[1];
    const int*   lidx = (const int*)d_in[2];
    const int*   hidx = (const int*)d_in[3];
    float* out = (float*)d_out;

    const size_t ws_needed =
        (size_t)(PART_ELEMS + META_INTS + NRED1 * 256) * sizeof(float);

    if (ws_size >= ws_needed) {
        float* part = (float*)d_ws;
        int*   mi   = (int*)(part + PART_ELEMS);
        float* mid  = (float*)(mi + META_INTS);
        pfe_setup<<<1, 256, 0, stream>>>(lidx, hidx, mi);
        pfe_dedup<<<NCHB, 256, 0, stream>>>(attn, refs, mi, part);
        pfe_red1<<<NRED1, 256, 0, stream>>>(part, mid);
        pfe_red2<<<1, 256, 0, stream>>>(mid, out);
    } else {
        pfe_zero<<<1, 256, 0, stream>>>(out);
        pfe_fallback<<<FNCH * M_DIM, 128, 0, stream>>>(attn, refs, lidx, hidx, out);
    }
}